// Round 6
// baseline (290.439 us; speedup 1.0000x reference)
//
#include <hip/hip_runtime.h>

// TT-linear v7: v5 (hardware-PASSED, 85us/dispatch) + G2 read-dedup.
// v5 analysis: LDS-pipe-bound; G2's B-operand (T1) was read 4x redundantly
// (4 waves with different rt2 roles read identical T1 lines). New G2 split:
//   vh = w>>1 : wave owns ONE v      (was vp2 = w>>2, two v)
//   rg2 = w&1 : wave owns FOUR rt2   (was rp2 = w&3, two rt2) -> aF[4][4]
// B-reads/slab/wave: 8 -> 4 (dup 4 -> 2). MFMA count unchanged (16/slab).
// All other code byte-identical to v5 (2 barriers/slab, single buffer,
// NO swizzle -- the swizzle was convicted as the v3/v4 correctness bug).
//   G1: T1[(n1,r1),(m2,v)] = C0^T @ X-slab   (A=C0^T regs, B=xpk; K=16 pad 32)
//   G2: T2[(n2,r2),n1]/v   = C1^T @ T1       (A=C1^T regs, B=T1 LDS b128, K=128)
//   G3: Y[n3,(n1,n2)]     += C2^T @ T2       (A=C2^T regs, B=T2 LDS b128, K=32/slab)
// T1 [v][m2][n1][r1]: elem = v*S3 + m2*S2 + n1*8 + r1  (S2=136, S3=2208)
// T2 [n2][n1][v][r2]: elem = n2*R2 + n1*R1 + v*8 + r2  (R1=40,  R2=672)
// G2 D-row map (proven v2/v5): row m=q*4+reg -> n2 = rt2*2+qh, r2 = 4*ql+reg
//   -> write addr (rt2*2+qh)*R2 + c*R1 + vh*8 + 4*ql, rt2 = rg2*4+i -> +i*1344.

typedef __attribute__((ext_vector_type(8))) short bf16x8;
typedef __attribute__((ext_vector_type(4))) float f32x4;

__device__ __forceinline__ unsigned short f2bf(float f) {
    unsigned u = __builtin_bit_cast(unsigned, f);
    u += 0x7FFFu + ((u >> 16) & 1u);   // RNE
    return (unsigned short)(u >> 16);
}

__device__ __forceinline__ unsigned f2bf_pk(float lo, float hi) {
#if __has_builtin(__builtin_amdgcn_cvt_pk_bf16_f32)
    typedef __attribute__((ext_vector_type(2))) __bf16 bf2;
    bf2 r = __builtin_amdgcn_cvt_pk_bf16_f32(lo, hi);
    return __builtin_bit_cast(unsigned, r);
#else
    return (unsigned)f2bf(lo) | ((unsigned)f2bf(hi) << 16);
#endif
}

union BF8 { bf16x8 v; unsigned short s[8]; unsigned u[4]; };
union U2  { uint2 d; unsigned u[2]; };

#define S2 136    // T1 m2-stride (elems)
#define S3 2208   // T1 v-stride  (= 16*S2 + 32 pad)
#define R1 40     // T2 n1-stride
#define R2 672    // T2 n2-stride (= 16*R1 + 32 pad)

#define MFMA32 __builtin_amdgcn_mfma_f32_16x16x32_bf16

__global__ __launch_bounds__(512, 4) void tt_mfma3_v7(
    const float* __restrict__ x, const float* __restrict__ c0,
    const float* __restrict__ c1, const float* __restrict__ c2,
    const float* __restrict__ bias, float* __restrict__ out)
{
    __shared__ __align__(16) unsigned short sT1[4 * S3];    // 17664 B
    __shared__ __align__(16) unsigned short sT2[16 * R2];   // 21504 B

    const int tid  = threadIdx.x;
    const int w    = tid >> 6;
    const int lane = tid & 63;
    const int q    = lane >> 4;
    const int c    = lane & 15;
    const int qh   = q >> 1, ql = q & 1;

    const int ct1  = w & 3;      // G1: col-tile (m2-group of 4)
    const int rtg1 = w >> 2;     // G1: row-tile group (4 tiles)
    const int rg2  = w & 1;      // G2: rt2-group of 4 (rt2 = rg2*4+i)
    const int vh   = w >> 1;     // G2: single v (0..3)
    // G3: n2 = w*2 + t

    // ---- loop-invariant LDS element offsets ----
    const int w1off = (c >> 2) * S3 + (ct1 * 4 + (c & 3)) * S2 + (rtg1 * 8 + qh) * 8 + 4 * ql;
    const int r2off = vh * S3 + q * S2 + c * 8;                       // + k4*544
    const int w2off = (rg2 * 8 + qh) * R2 + c * R1 + vh * 8 + 4 * ql; // + i*1344
    const int r3off = (w * 2) * R2 + c * R1 + q * 8;                  // + t*R2
    const int xcol  = ct1 * 64 + (c & 3) * 16 + (c >> 2) * 4;         // m2*16 + v*4

    const f32x4 zero = {0.f, 0.f, 0.f, 0.f};

    // ---- x as packed-bf16 register file: xpk[s] = G1 B-fragment, slab s ----
    // B[k=q*8+j][c] = x[m1=q*8+j][m2=ct1*4+(c&3)][m3=(c>>2)*4+s]; q>=2 zero pad.
    BF8 xpk[4];
    #pragma unroll
    for (int s = 0; s < 4; ++s)
        xpk[s].u[0] = xpk[s].u[1] = xpk[s].u[2] = xpk[s].u[3] = 0;

    auto issue_x = [&](int tb) {
        if (q < 2) {
            const float* xb = x + (size_t)(blockIdx.x * 8 + tb) * 4096;
            #pragma unroll
            for (int u = 0; u < 4; ++u) {       // pairwise: only 2 f32x4 live
                f32x4 t0 = *(const f32x4*)&xb[(q * 8 + 2 * u) * 256 + xcol];
                f32x4 t1 = *(const f32x4*)&xb[(q * 8 + 2 * u + 1) * 256 + xcol];
                #pragma unroll
                for (int s = 0; s < 4; ++s)
                    xpk[s].u[u] = f2bf_pk(t0[s], t1[s]);
            }
        }
    };

    issue_x(0);   // latency hidden under the fragment prologue

    // ---- fragment prologue (once per WG, serves 8 tokens) ----
    BF8 a0[4];                    // G1 A (C0^T), K=16 zero-padded: q>=2 rows zero
    #pragma unroll
    for (int i = 0; i < 4; ++i) {
        if (q < 2) {
            const int n1 = (rtg1 * 4 + i) * 2 + (c >> 3), r1 = c & 7;
            const float* p = &c0[(q * 8) * 128 + n1 * 8 + r1];
            #pragma unroll
            for (int u = 0; u < 4; ++u)
                a0[i].u[u] = f2bf_pk(p[(2 * u) * 128], p[(2 * u + 1) * 128]);
        } else {
            a0[i].u[0] = a0[i].u[1] = a0[i].u[2] = a0[i].u[3] = 0;
        }
    }
    BF8 aF[4][4];                 // G2 A (C1^T): [i = rt2-local][k4]
    #pragma unroll                //   row c -> n2 = (rg2*4+i)*2+(c>>3), r2 = c&7
    for (int i = 0; i < 4; ++i) { //   k = k4*32+q*8+jj -> (m2 = k4*4+q, r1 = jj)
        const int n2 = (rg2 * 4 + i) * 2 + (c >> 3), r2 = c & 7;
        #pragma unroll
        for (int k4 = 0; k4 < 4; ++k4) {
            const float* p = &c1[(k4 * 4 + q) * 128 + n2 * 8 + r2];
            #pragma unroll
            for (int u = 0; u < 4; ++u)
                aF[i][k4].u[u] = f2bf_pk(p[(2 * u) * 2048], p[(2 * u + 1) * 2048]);
        }
    }
    BF8 a2[4];                    // G3 A (C2^T) per slab: k = q*8+j -> (v=q, r2=j)
    #pragma unroll                //   m3 = v*4 + s  (matches xpk's m3 = (c>>2)*4+s)
    for (int s = 0; s < 4; ++s) {
        const float* p = &c2[(q * 4 + s) * 16 + c];
        #pragma unroll
        for (int u = 0; u < 4; ++u)
            a2[s].u[u] = f2bf_pk(p[(2 * u) * 256], p[(2 * u + 1) * 256]);
    }

    // ---- G1 body (v5 verbatim) ----
    auto G1 = [&](int s2) {
        #pragma unroll
        for (int i = 0; i < 4; ++i) {
            f32x4 d = MFMA32(a0[i].v, xpk[s2].v, zero, 0, 0, 0);
            U2 t; t.u[0] = f2bf_pk(d[0], d[1]); t.u[1] = f2bf_pk(d[2], d[3]);
            *(uint2*)&sT1[w1off + i * 16] = t.d;   // ds_write_b64
        }
    };

    for (int tok = 0; tok < 8; ++tok) {
        const int b = blockIdx.x * 8 + tok;

        f32x4 acc3[2] = {zero, zero};

        G1(0);
        #pragma unroll
        for (int s = 0; s < 4; ++s) {
            __syncthreads();                      // T1[s] ready
            // prefetch next token's x during slab 3's G2/G3 phases
            if (s == 3 && tok < 7) issue_x(tok + 1);
            // ---- G2 (dedup'd): 4 b128 reads, 16 MFMA, 4 b64 writes ----
            f32x4 acc2[4] = {zero, zero, zero, zero};
            __builtin_amdgcn_s_setprio(1);
            #pragma unroll
            for (int k4 = 0; k4 < 4; ++k4) {
                bf16x8 b0 = *(const bf16x8*)&sT1[r2off + k4 * 544];
                #pragma unroll
                for (int i = 0; i < 4; ++i)
                    acc2[i] = MFMA32(aF[i][k4].v, b0, acc2[i], 0, 0, 0);
            }
            __builtin_amdgcn_s_setprio(0);
            #pragma unroll
            for (int i = 0; i < 4; ++i) {
                U2 t;
                t.u[0] = f2bf_pk(acc2[i][0], acc2[i][1]);
                t.u[1] = f2bf_pk(acc2[i][2], acc2[i][3]);
                *(uint2*)&sT2[w2off + i * 1344] = t.d;   // ds_write_b64
            }
            __syncthreads();                      // T2 ready; T1 free
            // ---- G3 (v5 verbatim) ----
            {
                bf16x8 b0 = *(const bf16x8*)&sT2[r3off];
                bf16x8 b1 = *(const bf16x8*)&sT2[r3off + R2];
                acc3[0] = MFMA32(a2[s].v, b0, acc3[0], 0, 0, 0);
                acc3[1] = MFMA32(a2[s].v, b1, acc3[1], 0, 0, 0);
            }
            if (s < 3) G1(s + 1);                 // overlaps G3 phase
        }

        // ---- epilogue (v5 verbatim) ----
        float* outb = out + (size_t)b * 4096;
        #pragma unroll
        for (int t = 0; t < 2; ++t) {
            const int idx = c * 256 + (w * 2 + t) * 16 + 4 * q;
            f32x4 bv = *(const f32x4*)&bias[idx];
            f32x4 o = acc3[t] + bv;
            *(f32x4*)&outb[idx] = o;   // global_store_dwordx4
        }
    }
}

extern "C" void kernel_launch(void* const* d_in, const int* in_sizes, int n_in,
                              void* d_out, int out_size, void* d_ws, size_t ws_size,
                              hipStream_t stream) {
    const float* x    = (const float*)d_in[0];
    const float* c0   = (const float*)d_in[1];  // (1,16,16,8)
    const float* c1   = (const float*)d_in[2];  // (8,16,16,8)
    const float* c2   = (const float*)d_in[3];  // (8,16,16,1)
    const float* bias = (const float*)d_in[4];  // (4096,)
    float* out = (float*)d_out;

    tt_mfma3_v7<<<512, 512, 0, stream>>>(x, c0, c1, c2, bias, out);
}

// Round 8
// 179.605 us; speedup vs baseline: 1.6171x; 1.6171x over previous
//
#include <hip/hip_runtime.h>

// TT-linear v8: v5 (hardware-PASSED, 85us) re-blocked into 2 DOUBLE-slabs
// (v' = 0..7 m3-slices per slab S in {0,1}) -> barriers/WG 64 -> 32, 2x work
// and 2x ILP per phase. REGISTER-NEUTRAL vs v5 (v7's spill lesson): fragment
// arrays keep identical sizes (xpk[2][2], a2[2][2], aF[2][4], a0[4]); G2's
// two halves (h = 0,1) reuse the same acc2 registers sequentially.
//   G1: T1[v'][m2][(n1,r1)] = C0^T @ X   (A=C0^T regs, B=xpk; K=16 pad 32)
//   G2: T2[n2][n1][(v',r2)] = C1^T @ T1  (A=C1^T regs, B=T1 LDS b128, K=128)
//   G3: Y[n3,(n1,n2)]      += C2^T @ T2  (A=C2^T regs, B=T2 LDS b128, K=64/slab)
// m3 mapping (bijective): v' = h*4 + quad, m3 = quad*4 + 2h + S  (quad = c>>2
// in xpk / q in a2) -- so x float4 comp (m3&3) = 2h+S, matched in a2.
// T1 [v'][m2][n1][r1]: elem = v'*S3 + m2*S2 + n1*8 + r1   (S2=136, S3=2208)
// T2 [n2][n1][v'][r2]: elem = n2*R2 + n1*R1 + v'*8 + r2   (R1=72,  R2=1184)
// Bank audit (dw bank = (byte/4)%32): S3/2=1104 == 16 mod 32, R2/2=592 == 16,
// R1/2=36 == 4: G2 r b128 start 4(q+c)+16(j&1) -> 8/bank aggregate (min);
// G3 r b128 start 4((c+q)%8)+16h -> 8/bank (min); G1/G2 w b64 2-way (free).
// LDS 73216 B/WG -> 2 WG/CU (grid 512). Spill canaries: FETCH~37MB WRITE~71MB.
// (Round 7 was an infra failure -- container died twice; resubmitting v8
// unchanged so the experiment actually runs.)

typedef __attribute__((ext_vector_type(8))) short bf16x8;
typedef __attribute__((ext_vector_type(4))) float f32x4;

__device__ __forceinline__ unsigned short f2bf(float f) {
    unsigned u = __builtin_bit_cast(unsigned, f);
    u += 0x7FFFu + ((u >> 16) & 1u);   // RNE
    return (unsigned short)(u >> 16);
}

__device__ __forceinline__ unsigned f2bf_pk(float lo, float hi) {
#if __has_builtin(__builtin_amdgcn_cvt_pk_bf16_f32)
    typedef __attribute__((ext_vector_type(2))) __bf16 bf2;
    bf2 r = __builtin_amdgcn_cvt_pk_bf16_f32(lo, hi);
    return __builtin_bit_cast(unsigned, r);
#else
    return (unsigned)f2bf(lo) | ((unsigned)f2bf(hi) << 16);
#endif
}

union BF8 { bf16x8 v; unsigned short s[8]; unsigned u[4]; };
union U2  { uint2 d; unsigned u[2]; };

#define S2 136    // T1 m2-stride (elems)
#define S3 2208   // T1 v'-stride (= 16*S2 + 32 pad)
#define R1 72     // T2 n1-stride (= 64 + 8 pad)
#define R2 1184   // T2 n2-stride (= 16*R1 + 32 pad)

#define MFMA32 __builtin_amdgcn_mfma_f32_16x16x32_bf16

__global__ __launch_bounds__(512, 4) void tt_mfma3_v8(
    const float* __restrict__ x, const float* __restrict__ c0,
    const float* __restrict__ c1, const float* __restrict__ c2,
    const float* __restrict__ bias, float* __restrict__ out)
{
    __shared__ __align__(16) unsigned short sT1[8 * S3];    // 35328 B
    __shared__ __align__(16) unsigned short sT2[16 * R2];   // 37888 B

    const int tid  = threadIdx.x;
    const int w    = tid >> 6;
    const int lane = tid & 63;
    const int q    = lane >> 4;
    const int c    = lane & 15;
    const int qh   = q >> 1, ql = q & 1;

    const int ct1  = w & 3;      // G1: col-tile (m2-group of 4)
    const int rtg1 = w >> 2;     // G1: row-tile group (4 tiles)
    const int rp2  = w & 3;      // G2: rt2-pair
    const int vp2  = w >> 2;     // G2: v'-pair base (per half h: v' = h*4+vp2*2+j)
    // G3: n2 = w*2 + t

    // ---- loop-invariant LDS element offsets ----
    const int w1off = (c >> 2) * S3 + (ct1 * 4 + (c & 3)) * S2 + (rtg1 * 8 + qh) * 8 + 4 * ql;
    const int r2off = (vp2 * 2) * S3 + q * S2 + c * 8;               // + h*4*S3 + j*S3 + k4*544
    const int w2off = (rp2 * 4 + qh) * R2 + c * R1 + vp2 * 16 + 4 * ql; // + i*2*R2 + h*32 + j*8
    const int r3off = (w * 2) * R2 + c * R1 + q * 8;                 // + t*R2 + h*32
    const int xcol  = ct1 * 64 + (c & 3) * 16 + (c >> 2) * 4;        // m2*16 + quad*4

    const f32x4 zero = {0.f, 0.f, 0.f, 0.f};

    // ---- x register file: xpk[S][h] = G1 B-fragment (16 VGPRs total) ----
    // element [k=q*8+j][c] = x[m1=q*8+j][m2=ct1*4+(c&3)][m3=(c>>2)*4 + 2h + S]
    BF8 xpk[2][2];
    #pragma unroll
    for (int S = 0; S < 2; ++S)
        #pragma unroll
        for (int h = 0; h < 2; ++h)
            xpk[S][h].u[0] = xpk[S][h].u[1] = xpk[S][h].u[2] = xpk[S][h].u[3] = 0;

    auto issue_x = [&](int tb) {
        if (q < 2) {
            const float* xb = x + (size_t)(blockIdx.x * 8 + tb) * 4096;
            #pragma unroll
            for (int u = 0; u < 4; ++u) {       // pairwise: only 2 f32x4 live
                f32x4 t0 = *(const f32x4*)&xb[(q * 8 + 2 * u) * 256 + xcol];
                f32x4 t1 = *(const f32x4*)&xb[(q * 8 + 2 * u + 1) * 256 + xcol];
                #pragma unroll
                for (int S = 0; S < 2; ++S)
                    #pragma unroll
                    for (int h = 0; h < 2; ++h)
                        xpk[S][h].u[u] = f2bf_pk(t0[2 * h + S], t1[2 * h + S]);
            }
        }
    };

    issue_x(0);   // latency hidden under the fragment prologue

    // ---- fragment prologue (once per WG, serves 8 tokens) ----
    BF8 a0[4];                    // G1 A (C0^T), K=16 zero-padded: q>=2 rows zero
    #pragma unroll
    for (int i = 0; i < 4; ++i) {
        if (q < 2) {
            const int n1 = (rtg1 * 4 + i) * 2 + (c >> 3), r1 = c & 7;
            const float* p = &c0[(q * 8) * 128 + n1 * 8 + r1];
            #pragma unroll
            for (int u = 0; u < 4; ++u)
                a0[i].u[u] = f2bf_pk(p[(2 * u) * 128], p[(2 * u + 1) * 128]);
        } else {
            a0[i].u[0] = a0[i].u[1] = a0[i].u[2] = a0[i].u[3] = 0;
        }
    }
    BF8 aF[2][4];                 // G2 A (C1^T): k = k4*32+q*8+jj -> (m2,r1)
    #pragma unroll
    for (int i = 0; i < 2; ++i) {
        const int n2 = (rp2 * 2 + i) * 2 + (c >> 3), r2 = c & 7;
        #pragma unroll
        for (int k4 = 0; k4 < 4; ++k4) {
            const float* p = &c1[(k4 * 4 + q) * 128 + n2 * 8 + r2];
            #pragma unroll
            for (int u = 0; u < 4; ++u)
                aF[i][k4].u[u] = f2bf_pk(p[(2 * u) * 2048], p[(2 * u + 1) * 2048]);
        }
    }
    BF8 a2[2][2];                 // G3 A (C2^T): [S][h], k = q*8+j -> (v'=h*4+q, r2=j)
    #pragma unroll                //   m3 = q*4 + 2h + S  (same bijection as xpk)
    for (int S = 0; S < 2; ++S) {
        #pragma unroll
        for (int h = 0; h < 2; ++h) {
            const float* p = &c2[(q * 4 + 2 * h + S) * 16 + c];
            #pragma unroll
            for (int u = 0; u < 4; ++u)
                a2[S][h].u[u] = f2bf_pk(p[(2 * u) * 256], p[(2 * u + 1) * 256]);
        }
    }

    // ---- G1 body: both halves of slab S (8 MFMA, 8 b64 writes) ----
    auto G1 = [&](int S) {
        #pragma unroll
        for (int h = 0; h < 2; ++h) {
            #pragma unroll
            for (int i = 0; i < 4; ++i) {
                f32x4 d = MFMA32(a0[i].v, xpk[S][h].v, zero, 0, 0, 0);
                U2 t; t.u[0] = f2bf_pk(d[0], d[1]); t.u[1] = f2bf_pk(d[2], d[3]);
                *(uint2*)&sT1[w1off + h * 4 * S3 + i * 16] = t.d;   // ds_write_b64
            }
        }
    };

    for (int tok = 0; tok < 8; ++tok) {
        const int b = blockIdx.x * 8 + tok;

        f32x4 acc3[2] = {zero, zero};

        G1(0);
        #pragma unroll
        for (int S = 0; S < 2; ++S) {
            __syncthreads();                      // T1[S] ready
            // prefetch next token's x during the last slab's G2/G3 phases
            if (S == 1 && tok < 7) issue_x(tok + 1);
            // ---- G2: two halves, acc2 reused (register-neutral) ----
            #pragma unroll
            for (int h = 0; h < 2; ++h) {
                f32x4 acc2[2][2] = {{zero, zero}, {zero, zero}};
                __builtin_amdgcn_s_setprio(1);
                #pragma unroll
                for (int k4 = 0; k4 < 4; ++k4) {
                    bf16x8 b0 = *(const bf16x8*)&sT1[r2off + h * 4 * S3 + k4 * 544];
                    bf16x8 b1 = *(const bf16x8*)&sT1[r2off + h * 4 * S3 + S3 + k4 * 544];
                    #pragma unroll
                    for (int i = 0; i < 2; ++i) {
                        acc2[i][0] = MFMA32(aF[i][k4].v, b0, acc2[i][0], 0, 0, 0);
                        acc2[i][1] = MFMA32(aF[i][k4].v, b1, acc2[i][1], 0, 0, 0);
                    }
                }
                __builtin_amdgcn_s_setprio(0);
                #pragma unroll
                for (int i = 0; i < 2; ++i) {
                    #pragma unroll
                    for (int j = 0; j < 2; ++j) {
                        U2 t;
                        t.u[0] = f2bf_pk(acc2[i][j][0], acc2[i][j][1]);
                        t.u[1] = f2bf_pk(acc2[i][j][2], acc2[i][j][3]);
                        *(uint2*)&sT2[w2off + i * 2 * R2 + h * 32 + j * 8] = t.d;
                    }
                }
            }
            __syncthreads();                      // T2 ready; T1 free
            // ---- G3: K=64 per slab (2 n2-tiles x 2 halves) ----
            #pragma unroll
            for (int t = 0; t < 2; ++t) {
                #pragma unroll
                for (int h = 0; h < 2; ++h) {
                    bf16x8 b0 = *(const bf16x8*)&sT2[r3off + t * R2 + h * 32];
                    acc3[t] = MFMA32(a2[S][h].v, b0, acc3[t], 0, 0, 0);
                }
            }
            if (S == 0) G1(1);                    // overlaps G3 phase (v5 pattern)
        }

        // ---- epilogue: out[n1=c][n2=w*2+t][n3=q*4+r] ----
        float* outb = out + (size_t)b * 4096;
        #pragma unroll
        for (int t = 0; t < 2; ++t) {
            const int idx = c * 256 + (w * 2 + t) * 16 + 4 * q;
            f32x4 bv = *(const f32x4*)&bias[idx];
            f32x4 o = acc3[t] + bv;
            *(f32x4*)&outb[idx] = o;   // global_store_dwordx4
        }
    }
}

extern "C" void kernel_launch(void* const* d_in, const int* in_sizes, int n_in,
                              void* d_out, int out_size, void* d_ws, size_t ws_size,
                              hipStream_t stream) {
    const float* x    = (const float*)d_in[0];
    const float* c0   = (const float*)d_in[1];  // (1,16,16,8)
    const float* c1   = (const float*)d_in[2];  // (8,16,16,8)
    const float* c2   = (const float*)d_in[3];  // (8,16,16,1)
    const float* bias = (const float*)d_in[4];  // (4096,)
    float* out = (float*)d_out;

    tt_mfma3_v8<<<512, 512, 0, stream>>>(x, c0, c1, c2, bias, out);
}